// Round 5
// baseline (182.836 us; speedup 1.0000x reference)
//
#include <hip/hip_runtime.h>
#include <math.h>

// Native clang vector type: __builtin_nontemporal_store requires it
// (HIP_vector_type<float,4> is a struct and is rejected).
typedef float nt_float4 __attribute__((ext_vector_type(4)));

// Analytic inverse of [[R, t],[0,0,0,1]] with R from a normalized quaternion:
// inv = [[R^T, -R^T t],[0,0,0,1]].
struct Inv {
    float i00, i01, i02, it0;
    float i10, i11, i12, it1;
    float i20, i21, i22, it2;
};

__device__ __forceinline__ Inv make_inv(const float* __restrict__ q,
                                        const float* __restrict__ t, int b) {
    float w = q[b * 4 + 0], x = q[b * 4 + 1], y = q[b * 4 + 2], z = q[b * 4 + 3];
    float inv_n = 1.0f / sqrtf(w * w + x * x + y * y + z * z);
    w *= inv_n; x *= inv_n; y *= inv_n; z *= inv_n;
    float R00 = 1.f - 2.f * y * y - 2.f * z * z;
    float R01 = 2.f * x * y - 2.f * z * w;
    float R02 = 2.f * x * z + 2.f * y * w;
    float R10 = 2.f * x * y + 2.f * z * w;
    float R11 = 1.f - 2.f * x * x - 2.f * z * z;
    float R12 = 2.f * y * z - 2.f * x * w;
    float R20 = 2.f * x * z - 2.f * y * w;
    float R21 = 2.f * y * z + 2.f * x * w;
    float R22 = 1.f - 2.f * x * x - 2.f * y * y;
    float t0 = t[b * 3 + 0], t1 = t[b * 3 + 1], t2 = t[b * 3 + 2];
    Inv v;
    v.i00 = R00; v.i01 = R10; v.i02 = R20; v.it0 = -(R00 * t0 + R10 * t1 + R20 * t2);
    v.i10 = R01; v.i11 = R11; v.i12 = R21; v.it1 = -(R01 * t0 + R11 * t1 + R21 * t2);
    v.i20 = R02; v.i21 = R12; v.i22 = R22; v.it2 = -(R02 * t0 + R12 * t1 + R22 * t2);
    return v;
}

__device__ __forceinline__ void xf(const Inv& M, float px, float py, float pz,
                                   float& ox, float& oy, float& oz) {
    ox = fmaf(M.i00, px, fmaf(M.i01, py, fmaf(M.i02, pz, M.it0)));
    oy = fmaf(M.i10, px, fmaf(M.i11, py, fmaf(M.i12, pz, M.it1)));
    oz = fmaf(M.i20, px, fmaf(M.i21, py, fmaf(M.i22, pz, M.it2)));
}

__device__ __forceinline__ void nt_store(float4 v, float4* p) {
    nt_float4 nv = { v.x, v.y, v.z, v.w };
    __builtin_nontemporal_store(nv, (nt_float4*)p);
}

// Persistent kernel, block-level LDS staging (proven-correct round-2 phase
// structure: stage -> barrier -> in-place transform -> barrier -> coalesced
// store), plus grid-stride loop and one-iteration-ahead global prefetch so
// loads stay in flight across the barriers and the store phase.
//
// Hazard audit for 2 barriers/iter: phase-3 reads smem[tid+{0,256,512}] and
// next iteration's phase-1 writes the SAME per-thread slots -> program order
// covers it; every cross-thread edge (phase1->2, phase2->3, phase3->2')
// has a __syncthreads between.
__global__ __launch_bounds__(256) void realign_persist(
        const float4* __restrict__ pcd,
        const float* __restrict__ T_mis,
        const float* __restrict__ q,
        const float* __restrict__ t,
        float* __restrict__ out_mat,
        float4* __restrict__ out_pcd,
        int n_bchunks, int bcpb_shift, int B) {
    __shared__ float4 smem[768];   // 12 KB
    const int tid = threadIdx.x;

    // Fused batch_T_pred (B*16 = 512 elements) in block 0 only.
    if (blockIdx.x == 0) {
        for (int e = tid; e < B * 16; e += blockDim.x) {
            int b = e >> 4, i = (e >> 2) & 3, j = e & 3;
            const float* Tb = T_mis + b * 16;
            float val;
            if (i < 3) {
                Inv M = make_inv(q, t, b);
                float a0, a1, a2, it;
                if (i == 0)      { a0 = M.i00; a1 = M.i01; a2 = M.i02; it = M.it0; }
                else if (i == 1) { a0 = M.i10; a1 = M.i11; a2 = M.i12; it = M.it1; }
                else             { a0 = M.i20; a1 = M.i21; a2 = M.i22; it = M.it2; }
                val = fmaf(a0, Tb[j], fmaf(a1, Tb[4 + j], fmaf(a2, Tb[8 + j], it * Tb[12 + j])));
            } else {
                val = Tb[12 + j];
            }
            out_mat[e] = val;
        }
    }

    int bc = blockIdx.x;
    size_t base = (size_t)bc * 768u;
    float4 r0 = pcd[base + tid];
    float4 r1 = pcd[base + 256 + tid];
    float4 r2 = pcd[base + 512 + tid];

    while (true) {
        // Prefetch next block-chunk; stays in flight across both barriers.
        const int bcn = bc + gridDim.x;
        const bool more = (bcn < n_bchunks);
        float4 p0, p1, p2;
        if (more) {
            size_t nb = (size_t)bcn * 768u;
            p0 = pcd[nb + tid];
            p1 = pcd[nb + 256 + tid];
            p2 = pcd[nb + 512 + tid];
        }

        const int b = bc >> bcpb_shift;     // block-uniform -> scalarizes
        const Inv M = make_inv(q, t, b);

        // Phase 1: stage raw chunk in coalesced order.
        smem[tid]       = r0;
        smem[256 + tid] = r1;
        smem[512 + tid] = r2;
        __syncthreads();

        // Phase 2: each thread transforms 4 points (12 floats) in place.
        float4 v0 = smem[3 * tid + 0];
        float4 v1 = smem[3 * tid + 1];
        float4 v2 = smem[3 * tid + 2];
        float4 o0, o1, o2;
        xf(M, v0.x, v0.y, v0.z, o0.x, o0.y, o0.z);
        xf(M, v0.w, v1.x, v1.y, o0.w, o1.x, o1.y);
        xf(M, v1.z, v1.w, v2.x, o1.z, o1.w, o2.x);
        xf(M, v2.y, v2.z, v2.w, o2.y, o2.z, o2.w);
        smem[3 * tid + 0] = o0;
        smem[3 * tid + 1] = o1;
        smem[3 * tid + 2] = o2;
        __syncthreads();

        // Phase 3: coalesced readback + non-temporal streaming stores.
        float4 s0 = smem[tid];
        float4 s1 = smem[256 + tid];
        float4 s2 = smem[512 + tid];
        nt_store(s0, &out_pcd[base + tid]);
        nt_store(s1, &out_pcd[base + 256 + tid]);
        nt_store(s2, &out_pcd[base + 512 + tid]);

        if (!more) break;
        r0 = p0; r1 = p1; r2 = p2;
        bc = bcn;
        base = (size_t)bcn * 768u;
    }
}

extern "C" void kernel_launch(void* const* d_in, const int* in_sizes, int n_in,
                              void* d_out, int out_size, void* d_ws, size_t ws_size,
                              hipStream_t stream) {
    const float* pcd   = (const float*)d_in[0];  // (B, N, 3)
    const float* T_mis = (const float*)d_in[1];  // (B, 4, 4)
    const float* q     = (const float*)d_in[2];  // (B, 4)
    const float* t     = (const float*)d_in[3];  // (B, 3)
    float* out = (float*)d_out;

    const int B = in_sizes[2] / 4;                            // 32
    const long long N = (long long)in_sizes[0] / (3LL * B);   // 262144
    const int f4_per_batch = (int)(3 * N / 4);                // 196608
    const int bcpb = f4_per_batch / 768;                      // 256 block-chunks/batch
    int bcpb_shift = 0;
    while ((1 << bcpb_shift) < bcpb) bcpb_shift++;            // 8
    const int n_bchunks = B * bcpb;                           // 8192

    // 2048 persistent blocks (8/CU at 12 KB LDS) -> 4 chunks per block.
    const int blocks = 2048;
    realign_persist<<<blocks, 256, 0, stream>>>(
        (const float4*)pcd, T_mis, q, t,
        out, (float4*)(out + B * 16),
        n_bchunks, bcpb_shift, B);
}